// Round 1
// baseline (15.249 us; speedup 1.0000x reference)
//
#include <hip/hip_runtime.h>
#include <math.h>

#define RW 256          // render width  (u axis, output axis 0)
#define RH 256          // render height (v axis, output axis 1)
#define VN 256          // volume resolution per axis
#define TFN 128
#define MAXS 256

__global__ __launch_bounds__(256) void raycast_kernel(
    const float* __restrict__ vol,   // (256,256,256) row-major: x*65536+y*256+z
    const float* __restrict__ tf,    // (128,4)
    const float* __restrict__ lf3,   // (3,)
    float* __restrict__ out)         // (256,256,4)
{
    __shared__ float tf_s[TFN * 4];
    for (int i = threadIdx.x; i < TFN * 4; i += 256) tf_s[i] = tf[i];
    __syncthreads();

    const int tx = threadIdx.x & 15;
    const int ty = threadIdx.x >> 4;
    const int px = blockIdx.x * 16 + tx;   // u / output axis 0
    const int py = blockIdx.y * 16 + ty;   // v / output axis 1

    const float lfx = lf3[0], lfy = lf3[1], lfz = lf3[2];

    // view_dir = normalize(-look_from)
    float inv = rsqrtf(lfx * lfx + lfy * lfy + lfz * lfz);
    const float vdx = -lfx * inv, vdy = -lfy * inv, vdz = -lfz * inv;

    // right = normalize(cross(view_dir, (0,1,0))) = normalize((-vdz, 0, vdx))
    float rx = -vdz, rz = vdx;
    inv = rsqrtf(rx * rx + rz * rz);
    rx *= inv; rz *= inv;

    // up = normalize(cross(right, view_dir));  right.y == 0
    float ux = -rz * vdy;
    float uy = rz * vdx - rx * vdz;
    float uz = rx * vdy;
    inv = rsqrtf(ux * ux + uy * uy + uz * uz);
    ux *= inv; uy *= inv; uz *= inv;

    const float NEAR = 0.1f;
    const float near_h = 2.0f * tanf(0.5235987755982988f) * NEAR; // fov=30deg
    const float near_w = near_h;  // aspect = 1

    const float u = ((float)px + 0.5f) / (float)RW - 0.5f;
    const float v = ((float)py + 0.5f) / (float)RH - 0.5f;

    float rdx = NEAR * vdx + u * near_w * rx + v * near_h * ux;
    float rdy = NEAR * vdy              + v * near_h * uy;   // right.y == 0
    float rdz = NEAR * vdz + u * near_w * rz + v * near_h * uz;
    inv = rsqrtf(rdx * rdx + rdy * rdy + rdz * rdz);
    rdx *= inv; rdy *= inv; rdz *= inv;

    // slab test against [-1,1]^3
    const float sdx = (fabsf(rdx) < 1e-9f) ? 1e-9f : rdx;
    const float sdy = (fabsf(rdy) < 1e-9f) ? 1e-9f : rdy;
    const float sdz = (fabsf(rdz) < 1e-9f) ? 1e-9f : rdz;
    const float dfx = 1.0f / sdx, dfy = 1.0f / sdy, dfz = 1.0f / sdz;
    const float t1x = (-1.0f - lfx) * dfx, t2x = (1.0f - lfx) * dfx;
    const float t1y = (-1.0f - lfy) * dfy, t2y = (1.0f - lfy) * dfy;
    const float t1z = (-1.0f - lfz) * dfz, t2z = (1.0f - lfz) * dfz;
    const float tmin = fmaxf(fminf(t1x, t2x), fmaxf(fminf(t1y, t2y), fminf(t1z, t2z)));
    const float tmax = fminf(fmaxf(t1x, t2x), fminf(fmaxf(t1y, t2y), fmaxf(t1z, t2z)));
    const bool hit = (tmax >= 0.0f) && (tmin <= tmax);
    const float entry = fmaxf(tmin, 0.0f);
    const float ray_len = fmaxf(tmax - entry, 0.0f);

    // n_samples = clip(ceil(VOL_DIAG * ray_len / 2), 1, 256); VOL_DIAG = 256*sqrt(3)
    const float nsf = fminf(fmaxf(ceilf(443.4050067376326f * ray_len / 2.0f), 1.0f),
                            (float)MAXS);
    const int n = (int)nsf;
    const float dt = ray_len / nsf;

    float acc_r = 0.0f, acc_g = 0.0f, acc_b = 0.0f, acc_a = 0.0f;

    if (hit) {
        const float scale = 255.0f - 1e-4f;  // (shp - 1 - 1e-4)
        for (int k = 0; k < n; ++k) {
            if (acc_a >= 0.99f) break;
            const float t = entry + ((float)k + 0.5f) * dt;
            const float posx = lfx + rdx * t;
            const float posy = lfy + rdy * t;
            const float posz = lfz + rdz * t;

            // trilinear sample
            const float pxf = fminf(fmaxf(0.5f * posx + 0.5f, 0.0f), 1.0f) * scale;
            const float pyf = fminf(fmaxf(0.5f * posy + 0.5f, 0.0f), 1.0f) * scale;
            const float pzf = fminf(fmaxf(0.5f * posz + 0.5f, 0.0f), 1.0f) * scale;
            const float flx = floorf(pxf), fly = floorf(pyf), flz = floorf(pzf);
            const float fx = pxf - flx, fy = pyf - fly, fz = pzf - flz;
            const int x0 = (int)flx, y0 = (int)fly, z0 = (int)flz;
            const int x1 = min(x0 + 1, VN - 1);
            const int y1 = min(y0 + 1, VN - 1);
            const int z1 = min(z0 + 1, VN - 1);

            const int bx0 = x0 << 16, bx1 = x1 << 16;      // *65536
            const int by0 = y0 << 8,  by1 = y1 << 8;       // *256
            const float c000 = vol[bx0 + by0 + z0];
            const float c100 = vol[bx1 + by0 + z0];
            const float c010 = vol[bx0 + by1 + z0];
            const float c110 = vol[bx1 + by1 + z0];
            const float c001 = vol[bx0 + by0 + z1];
            const float c101 = vol[bx1 + by0 + z1];
            const float c011 = vol[bx0 + by1 + z1];
            const float c111 = vol[bx1 + by1 + z1];

            const float c00 = c000 * (1.0f - fx) + c100 * fx;
            const float c10 = c010 * (1.0f - fx) + c110 * fx;
            const float c01 = c001 * (1.0f - fx) + c101 * fx;
            const float c11 = c011 * (1.0f - fx) + c111 * fx;
            const float c0 = c00 * (1.0f - fy) + c10 * fy;
            const float c1 = c01 * (1.0f - fy) + c11 * fy;
            const float intensity = c0 * (1.0f - fz) + c1 * fz;

            // transfer function lerp
            const float ti = fminf(fmaxf(intensity, 0.0f), 1.0f) * (float)(TFN - 1);
            const float tl = floorf(ti);
            const float tfr = ti - tl;
            const int i0 = (int)tl;
            const int i1 = min(i0 + 1, TFN - 1);
            const float om = 1.0f - tfr;
            const float r = tf_s[i0 * 4 + 0] * om + tf_s[i1 * 4 + 0] * tfr;
            const float g = tf_s[i0 * 4 + 1] * om + tf_s[i1 * 4 + 1] * tfr;
            const float b = tf_s[i0 * 4 + 2] * om + tf_s[i1 * 4 + 2] * tfr;
            const float a = tf_s[i0 * 4 + 3] * om + tf_s[i1 * 4 + 3] * tfr;

            // SAMPLING_RATE == 1 -> pow(x, 1.0) == x
            const float alpha = 1.0f - fmaxf(1.0f - a, 1e-7f);
            const float w = (1.0f - acc_a) * alpha;
            acc_r += w * r;
            acc_g += w * g;
            acc_b += w * b;
            acc_a += w;
        }
    }

    const int o = (px * RH + py) * 4;
    out[o + 0] = acc_r;
    out[o + 1] = acc_g;
    out[o + 2] = acc_b;
    out[o + 3] = acc_a;
}

extern "C" void kernel_launch(void* const* d_in, const int* in_sizes, int n_in,
                              void* d_out, int out_size, void* d_ws, size_t ws_size,
                              hipStream_t stream) {
    const float* vol = (const float*)d_in[0];
    const float* tf  = (const float*)d_in[1];
    const float* lf  = (const float*)d_in[2];
    float* out = (float*)d_out;

    dim3 grid(RW / 16, RH / 16);   // 16x16 pixel tiles, 256 threads each
    raycast_kernel<<<grid, 256, 0, stream>>>(vol, tf, lf, out);
}